// Round 1
// baseline (339.160 us; speedup 1.0000x reference)
//
#include <hip/hip_runtime.h>

typedef _Float16 half_t;
typedef _Float16 f16x8 __attribute__((ext_vector_type(8)));
typedef _Float16 f16x4 __attribute__((ext_vector_type(4)));
typedef float f32x4 __attribute__((ext_vector_type(4)));

#define NN 6144
#define IN_DIM 512
#define DD 256
#define OUT_DIM 128

__device__ __forceinline__ f32x4 mfma16(f16x8 a, f16x8 b, f32x4 c) {
  return __builtin_amdgcn_mfma_f32_16x16x32_f16(a, b, c, 0, 0, 0);
}

// ---------------- convert x (f32 -> f16) ----------------
__global__ void cvt_x_kernel(const float* __restrict__ x, half_t* __restrict__ xh) {
  int idx = (blockIdx.x * 256 + threadIdx.x) * 4;
  float4 v = *(const float4*)(x + idx);
  f16x4 h;
  h[0] = (half_t)v.x; h[1] = (half_t)v.y; h[2] = (half_t)v.z; h[3] = (half_t)v.w;
  *(f16x4*)(xh + idx) = h;
}

// ---------------- convert + transpose weights ----------------
// WT[v][n][k] = W_v[k][n]  (3 x 256 x 512), pWT[o][k] = proj_W[k][o] (128 x 256)
__global__ void cvt_w_kernel(const float* __restrict__ W0, const float* __restrict__ W1,
                             const float* __restrict__ W2, const float* __restrict__ pW,
                             half_t* __restrict__ WT, half_t* __restrict__ pWT) {
  int y = blockIdx.y;
  int idx = blockIdx.x * 256 + threadIdx.x;
  if (y < 3) {
    const float* W = (y == 0) ? W0 : (y == 1) ? W1 : W2;
    int k = idx >> 8, n = idx & 255;
    WT[(size_t)y * DD * IN_DIM + (size_t)n * IN_DIM + k] = (half_t)W[idx];
  } else if (idx < DD * OUT_DIM) {
    int k = idx >> 7, o = idx & 127;
    pWT[(size_t)o * DD + k] = (half_t)pW[idx];
  }
}

// ---------------- GEMM1: hT[v][d][i] = (x @ W_v)^T in f16 ----------------
// block: 64 rows(i) x 256 cols(d), 4 waves (each 64 cols), K=512
__global__ __launch_bounds__(256, 2) void gemm1_kernel(
    const half_t* __restrict__ xh, const half_t* __restrict__ WT,
    half_t* __restrict__ hT) {
  int v = blockIdx.y;
  int i0 = blockIdx.x * 64;
  int t = threadIdx.x;
  int lane = t & 63, w = t >> 6;
  int lr = lane & 15, lg = lane >> 4;
  const half_t* Wv = WT + (size_t)v * DD * IN_DIM;
  f32x4 acc[4][4] = {};
  for (int kt = 0; kt < 16; ++kt) {
    int k = kt * 32 + lg * 8;
    f16x8 af[4], bf[4];
#pragma unroll
    for (int mf = 0; mf < 4; ++mf)
      af[mf] = *(const f16x8*)(xh + (size_t)(i0 + mf * 16 + lr) * IN_DIM + k);
#pragma unroll
    for (int nf = 0; nf < 4; ++nf)
      bf[nf] = *(const f16x8*)(Wv + (size_t)(w * 64 + nf * 16 + lr) * IN_DIM + k);
#pragma unroll
    for (int mf = 0; mf < 4; ++mf)
#pragma unroll
      for (int nf = 0; nf < 4; ++nf)
        acc[mf][nf] = mfma16(af[mf], bf[nf], acc[mf][nf]);
  }
  // transpose epilogue via LDS (per-wave region, XOR-swizzled rows)
  __shared__ half_t tr[4][64 * 64];
  char* trw = (char*)tr[w];
#pragma unroll
  for (int mf = 0; mf < 4; ++mf)
#pragma unroll
    for (int nf = 0; nf < 4; ++nf)
#pragma unroll
      for (int r = 0; r < 4; ++r) {
        int dl = nf * 16 + lr;
        int il = mf * 16 + lg * 4 + r;
        unsigned addr = (unsigned)((dl * 128 + il * 2) ^ ((dl & 7) << 4));
        *(half_t*)(trw + addr) = (half_t)acc[mf][nf][r];
      }
  __syncthreads();
  half_t* hTv = hT + (size_t)v * DD * NN;
#pragma unroll
  for (int c = 0; c < 8; ++c) {
    unsigned addr = (unsigned)((lane * 128 + c * 16) ^ ((lane & 7) << 4));
    f16x8 val = *(const f16x8*)(trw + addr);
    *(f16x8*)(hTv + (size_t)(w * 64 + lane) * NN + i0 + c * 8) = val;
  }
}

// ---------------- e1/e2 scores ----------------
__global__ void escore_kernel(const half_t* __restrict__ hT,
    const float* __restrict__ as0, const float* __restrict__ as1, const float* __restrict__ as2,
    const float* __restrict__ ad0, const float* __restrict__ ad1, const float* __restrict__ ad2,
    float* __restrict__ e1, float* __restrict__ e2) {
  int v = blockIdx.y;
  int i = blockIdx.x * 256 + threadIdx.x;
  const float* as = (v == 0) ? as0 : (v == 1) ? as1 : as2;
  const float* ad = (v == 0) ? ad0 : (v == 1) ? ad1 : ad2;
  const half_t* h = hT + (size_t)v * DD * NN;
  float acc1 = 0.f, acc2 = 0.f;
  for (int d = 0; d < DD; ++d) {
    float hv = (float)h[(size_t)d * NN + i];
    acc1 = fmaf(hv, as[d], acc1);
    acc2 = fmaf(hv, ad[d], acc2);
  }
  e1[v * NN + i] = acc1;
  e2[v * NN + i] = acc2;
}

// ---------------- e2 max per view ----------------
__global__ void e2max_kernel(const float* __restrict__ e2, float* __restrict__ e2m) {
  int v = blockIdx.x;
  __shared__ float red[256];
  float m = -1e30f;
  for (int i = threadIdx.x; i < NN; i += 256) m = fmaxf(m, e2[v * NN + i]);
  red[threadIdx.x] = m;
  __syncthreads();
  for (int s = 128; s > 0; s >>= 1) {
    if (threadIdx.x < s) red[threadIdx.x] = fmaxf(red[threadIdx.x], red[threadIdx.x + s]);
    __syncthreads();
  }
  if (threadIdx.x == 0) e2m[v] = red[0];
}

// ---------------- fused GAT aggregation (flash-style, static max bound) ----------------
// grid (96, 3): 64 rows per block, j-tiles of 64. outv[v][i][d] f16.
__global__ __launch_bounds__(256, 2) void gat_kernel(
    const int* __restrict__ adj0, const int* __restrict__ adj1, const int* __restrict__ adj2,
    const half_t* __restrict__ hT, const float* __restrict__ e1g,
    const float* __restrict__ e2g, const float* __restrict__ e2maxg,
    half_t* __restrict__ outv) {
  int v = blockIdx.y;
  const int* __restrict__ adj = (v == 0) ? adj0 : (v == 1) ? adj1 : adj2;
  int i0 = blockIdx.x * 64;
  int t = threadIdx.x;
  int lane = t & 63, w = t >> 6;
  int lr = lane & 15, lg = lane >> 4;
  int jq = t & 15;   // quad-of-j index 0..15
  int rg = t >> 4;   // row group 0..15
  __shared__ half_t P_lds[64 * 64];
  __shared__ float e1_lds[64], m_lds[64], l_lds[64];
  if (t < 64) {
    float e1i = e1g[v * NN + i0 + t];
    e1_lds[t] = e1i;
    float mm = e1i + e2maxg[v];
    m_lds[t] = (mm > 0.f) ? mm : 0.2f * mm;  // lrelu upper bound of row max
  }
  const half_t* hTv = hT + (size_t)v * DD * NN;
  const float* e2v = e2g + v * NN;
  f32x4 acc[4][4] = {};
  float lpart[4] = {0.f, 0.f, 0.f, 0.f};
  // prefetch adj tile 0
  int4 aj[4];
#pragma unroll
  for (int it = 0; it < 4; ++it)
    aj[it] = *(const int4*)(adj + (size_t)(i0 + it * 16 + rg) * NN + jq * 4);
  __syncthreads();
  for (int jt = 0; jt < 96; ++jt) {
    int j0 = jt * 64;
    // B-fragments (V = hT rows), from L2
    f16x8 bfr[2][4];
#pragma unroll
    for (int kf = 0; kf < 2; ++kf)
#pragma unroll
      for (int nf = 0; nf < 4; ++nf)
        bfr[kf][nf] = *(const f16x8*)(hTv + (size_t)(w * 64 + nf * 16 + lr) * NN +
                                      j0 + kf * 32 + lg * 8);
    float4 e2q = *(const float4*)(e2v + j0 + jq * 4);
    // compute P tile into swizzled LDS
#pragma unroll
    for (int it = 0; it < 4; ++it) {
      int il = it * 16 + rg;
      float m = m_lds[il];
      float e1i = e1_lds[il];
      int a4[4] = {aj[it].x, aj[it].y, aj[it].z, aj[it].w};
      float e2a[4] = {e2q.x, e2q.y, e2q.z, e2q.w};
      f16x4 ph;
      float s = 0.f;
#pragma unroll
      for (int c = 0; c < 4; ++c) {
        float e = e1i + e2a[c];
        e = (e > 0.f) ? e : 0.2f * e;
        float p = (a4[c] > 0) ? __expf(e - m) : 0.f;
        s += p;
        ph[c] = (half_t)p;
      }
      lpart[it] += s;
      unsigned addr = (unsigned)((il * 128 + jq * 8) ^ ((il & 7) << 4));
      *(f16x4*)((char*)P_lds + addr) = ph;
    }
    __syncthreads();
    // prefetch adj for next tile (hidden under MFMA)
    if (jt + 1 < 96) {
#pragma unroll
      for (int it = 0; it < 4; ++it)
        aj[it] = *(const int4*)(adj + (size_t)(i0 + it * 16 + rg) * NN + (j0 + 64) + jq * 4);
    }
    // PV MFMA
#pragma unroll
    for (int kf = 0; kf < 2; ++kf)
#pragma unroll
      for (int mf = 0; mf < 4; ++mf) {
        int row = mf * 16 + lr;
        unsigned addr = (unsigned)((row * 128 + kf * 64 + lg * 16) ^ ((row & 7) << 4));
        f16x8 af = *(const f16x8*)((const char*)P_lds + addr);
#pragma unroll
        for (int nf = 0; nf < 4; ++nf)
          acc[mf][nf] = mfma16(af, bfr[kf][nf], acc[mf][nf]);
      }
    __syncthreads();
  }
  // reduce row sums l
#pragma unroll
  for (int it = 0; it < 4; ++it) {
    float s = lpart[it];
    s += __shfl_xor(s, 1); s += __shfl_xor(s, 2);
    s += __shfl_xor(s, 4); s += __shfl_xor(s, 8);
    if (lr == 0) l_lds[it * 16 + rg] = s;
  }
  __syncthreads();
  half_t* ov = outv + (size_t)v * NN * DD;
#pragma unroll
  for (int mf = 0; mf < 4; ++mf)
#pragma unroll
    for (int r = 0; r < 4; ++r) {
      int il = mf * 16 + lg * 4 + r;
      float li = l_lds[il];
      float rli = (li > 0.f) ? 1.f / li : 0.f;
#pragma unroll
      for (int nf = 0; nf < 4; ++nf)
        ov[(size_t)(i0 + il) * DD + w * 64 + nf * 16 + lr] = (half_t)(acc[mf][nf][r] * rli);
    }
}

// ---------------- proj + LN + weighted combine ----------------
// grid 96: 64 rows per block; wave w -> rows [w*16, w*16+16), cols 0..127
__global__ __launch_bounds__(256, 2) void proj_kernel(
    const half_t* __restrict__ outv, const half_t* __restrict__ pWT,
    const float* __restrict__ proj_b, const float* __restrict__ ln_g,
    const float* __restrict__ ln_b, const float* __restrict__ alpha,
    float* __restrict__ out) {
  int i0 = blockIdx.x * 64;
  int t = threadIdx.x, lane = t & 63, w = t >> 6;
  int lr = lane & 15, lg = lane >> 4;
  float a0 = alpha[0], a1 = alpha[1], a2 = alpha[2];
  float am = fmaxf(a0, fmaxf(a1, a2));
  float x0 = __expf(a0 - am), x1 = __expf(a1 - am), x2 = __expf(a2 - am);
  float inv = 1.f / (x0 + x1 + x2);
  float wv[3] = {x0 * inv, x1 * inv, x2 * inv};
  f32x4 zacc[8] = {};
  float pb[8], gg[8], bb[8];
#pragma unroll
  for (int nf = 0; nf < 8; ++nf) {
    pb[nf] = proj_b[nf * 16 + lr];
    gg[nf] = ln_g[nf * 16 + lr];
    bb[nf] = ln_b[nf * 16 + lr];
  }
  for (int v = 0; v < 3; ++v) {
    f32x4 yac[8] = {};
    const half_t* ovv = outv + (size_t)v * NN * DD;
    for (int kt = 0; kt < 8; ++kt) {
      int k = kt * 32 + lg * 8;
      f16x8 af = *(const f16x8*)(ovv + (size_t)(i0 + w * 16 + lr) * DD + k);
#pragma unroll
      for (int nf = 0; nf < 8; ++nf) {
        f16x8 bf = *(const f16x8*)(pWT + (size_t)(nf * 16 + lr) * DD + k);
        yac[nf] = mfma16(af, bf, yac[nf]);
      }
    }
#pragma unroll
    for (int r = 0; r < 4; ++r) {
      float s = 0.f, q = 0.f;
#pragma unroll
      for (int nf = 0; nf < 8; ++nf) {
        float y = yac[nf][r] + pb[nf];
        yac[nf][r] = y;
        s += y; q += y * y;
      }
      s += __shfl_xor(s, 1); s += __shfl_xor(s, 2);
      s += __shfl_xor(s, 4); s += __shfl_xor(s, 8);
      q += __shfl_xor(q, 1); q += __shfl_xor(q, 2);
      q += __shfl_xor(q, 4); q += __shfl_xor(q, 8);
      float mean = s * (1.f / 128.f);
      float var = q * (1.f / 128.f) - mean * mean;
      float rstd = rsqrtf(var + 1e-5f);
      float wvv = wv[v];
#pragma unroll
      for (int nf = 0; nf < 8; ++nf)
        zacc[nf][r] += wvv * (yac[nf][r] - mean) * rstd;
    }
  }
#pragma unroll
  for (int nf = 0; nf < 8; ++nf)
#pragma unroll
    for (int r = 0; r < 4; ++r) {
      int row = i0 + w * 16 + lg * 4 + r;
      float z = zacc[nf][r] * gg[nf] + bb[nf];
      if (!isfinite(z)) z = 0.f;
      out[(size_t)row * OUT_DIM + nf * 16 + lr] = z;
    }
  if (blockIdx.x == 0 && t < 3) out[(size_t)NN * OUT_DIM + t] = wv[t];
}

// ---------------- launch ----------------
extern "C" void kernel_launch(void* const* d_in, const int* in_sizes, int n_in,
                              void* d_out, int out_size, void* d_ws, size_t ws_size,
                              hipStream_t stream) {
  const float* x      = (const float*)d_in[0];
  const int*   adj_cf = (const int*)d_in[1];
  const int*   adj_or = (const int*)d_in[2];
  const int*   adj_pe = (const int*)d_in[3];
  const float* W_cf   = (const float*)d_in[4];
  const float* as_cf  = (const float*)d_in[5];
  const float* ad_cf  = (const float*)d_in[6];
  const float* W_or   = (const float*)d_in[7];
  const float* as_or  = (const float*)d_in[8];
  const float* ad_or  = (const float*)d_in[9];
  const float* W_pe   = (const float*)d_in[10];
  const float* as_pe  = (const float*)d_in[11];
  const float* ad_pe  = (const float*)d_in[12];
  const float* proj_W = (const float*)d_in[13];
  const float* proj_b = (const float*)d_in[14];
  const float* ln_g   = (const float*)d_in[15];
  const float* ln_b   = (const float*)d_in[16];
  const float* alpha  = (const float*)d_in[17];

  char* ws = (char*)d_ws;
  half_t* xh   = (half_t*)(ws + 0);              // 6144*512*2      = 6291456
  half_t* WT   = (half_t*)(ws + 6291456);        // 3*256*512*2     = 786432
  half_t* pWT  = (half_t*)(ws + 7077888);        // 128*256*2       = 65536
  half_t* hT   = (half_t*)(ws + 7143424);        // 3*256*6144*2    = 9437184
  float*  e1   = (float*)(ws + 16580608);        // 3*6144*4        = 73728
  float*  e2   = (float*)(ws + 16654336);        // 73728
  float*  e2m  = (float*)(ws + 16728064);        // 16
  half_t* outv = (half_t*)(ws + 16728080);       // 3*6144*256*2    = 9437184

  cvt_x_kernel<<<3072, 256, 0, stream>>>(x, xh);
  cvt_w_kernel<<<dim3(512, 4), 256, 0, stream>>>(W_cf, W_or, W_pe, proj_W, WT, pWT);
  gemm1_kernel<<<dim3(96, 3), 256, 0, stream>>>(xh, WT, hT);
  escore_kernel<<<dim3(24, 3), 256, 0, stream>>>(hT, as_cf, as_or, as_pe,
                                                 ad_cf, ad_or, ad_pe, e1, e2);
  e2max_kernel<<<3, 256, 0, stream>>>(e2, e2m);
  gat_kernel<<<dim3(96, 3), 256, 0, stream>>>(adj_cf, adj_or, adj_pe, hT, e1, e2, e2m, outv);
  proj_kernel<<<96, 256, 0, stream>>>(outv, pWT, proj_b, ln_g, ln_b, alpha, (float*)d_out);
}